// Round 1
// baseline (1398.111 us; speedup 1.0000x reference)
//
#include <hip/hip_runtime.h>

// AxialAttention on MI355X (gfx950).
// Shapes: q,k,v (2,8,512,32,64) fp32. B = 2*8*32 = 512 batches, L = 512, D = 64.
// qf[Bi, l, d] = q[bh*1048576 + l*2048 + d2*64 + d]  where bh = Bi>>5, d2 = Bi&31.
// Outputs: out (16,777,216 f32, same layout as q) then probs (512,512,512 f32).
//
// One workgroup = 4 waves = one (batch, 64-row q-tile). Each wave owns 16 q rows.
// S (16x512 per wave) lives entirely in MFMA C-fragments (32 x f32x4 = 128 VGPRs).
// Softmax via in-register butterfly over the 16 lanes of each quad.
// PV: P transposed C-layout -> A-layout through a small per-wave LDS tile.

typedef __bf16 b16x8 __attribute__((ext_vector_type(8)));
typedef float f32x4 __attribute__((ext_vector_type(4)));

#define NEG_INF (-1e9f)

__global__ __launch_bounds__(256, 2)
void axial_attn_kernel(const float* __restrict__ q,
                       const float* __restrict__ k,
                       const float* __restrict__ v,
                       const float* __restrict__ am,
                       const float* __restrict__ hm,
                       float* __restrict__ out,
                       float* __restrict__ probs) {
    const int bid  = blockIdx.x;      // 0..4095
    const int Bi   = bid >> 3;        // batch 0..511
    const int qt   = bid & 7;         // q-tile 0..7
    const int bh   = Bi >> 5;         // 0..15
    const int d2   = Bi & 31;         // 0..31
    const int tid  = threadIdx.x;
    const int w    = tid >> 6;        // wave 0..3
    const int lane = tid & 63;
    const int ln   = lane & 15;
    const int quad = lane >> 4;
    const int q0   = qt * 64 + w * 16;  // first q row of this wave

    const size_t base = (size_t)bh * 1048576 + (size_t)d2 * 64;
    const float* qb = q + base;
    const float* kb = k + base;
    const float* vb = v + base;

    // ---- Q A-fragments: lane holds Q[q0+ln][c*32 + quad*8 + j], j=0..7
    b16x8 aq0, aq1;
    {
        const float* qrow = qb + (size_t)(q0 + ln) * 2048 + quad * 8;
        #pragma unroll
        for (int j = 0; j < 8; ++j) {
            aq0[j] = (__bf16)qrow[j];
            aq1[j] = (__bf16)qrow[32 + j];
        }
    }

    // ---- S = Q K^T over 32 k-tiles of 16 columns; C-frag: row=quad*4+r, col=lane&15
    f32x4 acc[32];
    #pragma unroll
    for (int t = 0; t < 32; ++t) acc[t] = (f32x4){0.f, 0.f, 0.f, 0.f};

    #pragma unroll
    for (int t = 0; t < 32; ++t) {
        // B-frag: lane holds K[t*16 + ln][c*32 + quad*8 + j]
        const float* krow = kb + (size_t)(t * 16 + ln) * 2048 + quad * 8;
        b16x8 bk0, bk1;
        #pragma unroll
        for (int j = 0; j < 8; ++j) {
            bk0[j] = (__bf16)krow[j];
            bk1[j] = (__bf16)krow[32 + j];
        }
        acc[t] = __builtin_amdgcn_mfma_f32_16x16x32_bf16(aq0, bk0, acc[t], 0, 0, 0);
        acc[t] = __builtin_amdgcn_mfma_f32_16x16x32_bf16(aq1, bk1, acc[t], 0, 0, 0);
    }

    // ---- scale, attention mask, row max
    const int rowbase = q0 + quad * 4;
    const float* amp = am + (size_t)rowbase * 512 + ln;
    const float* hmp = hm + (size_t)rowbase * 512 + ln;

    float mrow[4] = {NEG_INF, NEG_INF, NEG_INF, NEG_INF};
    #pragma unroll
    for (int t = 0; t < 32; ++t) {
        #pragma unroll
        for (int r = 0; r < 4; ++r) {
            float s = acc[t][r] * 0.125f;               // 1/sqrt(64)
            float m = amp[r * 512 + t * 16];
            s = (m == 0.0f) ? NEG_INF : s;
            acc[t][r] = s;
            mrow[r] = fmaxf(mrow[r], s);
        }
    }
    #pragma unroll
    for (int off = 1; off < 16; off <<= 1) {
        #pragma unroll
        for (int r = 0; r < 4; ++r)
            mrow[r] = fmaxf(mrow[r], __shfl_xor(mrow[r], off, 64));
    }

    // ---- exp and row sum
    float srow[4] = {0.f, 0.f, 0.f, 0.f};
    #pragma unroll
    for (int t = 0; t < 32; ++t) {
        #pragma unroll
        for (int r = 0; r < 4; ++r) {
            float e = __expf(acc[t][r] - mrow[r]);
            acc[t][r] = e;
            srow[r] += e;
        }
    }
    #pragma unroll
    for (int off = 1; off < 16; off <<= 1) {
        #pragma unroll
        for (int r = 0; r < 4; ++r)
            srow[r] += __shfl_xor(srow[r], off, 64);
    }
    float inv[4];
    #pragma unroll
    for (int r = 0; r < 4; ++r) inv[r] = 1.0f / srow[r];

    // ---- probs = softmax * head_mask; write to global, keep in acc for PV
    float* pout = probs + (size_t)Bi * 262144 + (size_t)rowbase * 512 + ln;
    #pragma unroll
    for (int t = 0; t < 32; ++t) {
        #pragma unroll
        for (int r = 0; r < 4; ++r) {
            float p = acc[t][r] * inv[r] * hmp[r * 512 + t * 16];
            acc[t][r] = p;
            pout[r * 512 + t * 16] = p;
        }
    }

    // ---- O = P V : transpose P (C-layout) -> A-layout via per-wave LDS tile
    __shared__ __bf16 plds[4][16][40];   // row stride 40 bf16 = 80 B (16B-aligned rows)
    f32x4 oacc[4];
    #pragma unroll
    for (int n = 0; n < 4; ++n) oacc[n] = (f32x4){0.f, 0.f, 0.f, 0.f};

    #pragma unroll
    for (int kc = 0; kc < 16; ++kc) {     // 16 K-chunks of 32
        #pragma unroll
        for (int t = 0; t < 2; ++t)
            #pragma unroll
            for (int r = 0; r < 4; ++r)
                plds[w][quad * 4 + r][t * 16 + ln] = (__bf16)acc[kc * 2 + t][r];
        __syncthreads();
        // A-frag: lane holds P[ln][kc*32 + quad*8 + j]
        b16x8 pa = *(const b16x8*)&plds[w][ln][quad * 8];
        #pragma unroll
        for (int n = 0; n < 4; ++n) {
            // B-frag: lane holds V[kc*32 + quad*8 + j][n*16 + ln]
            const float* vrow = vb + (size_t)(kc * 32 + quad * 8) * 2048 + n * 16 + ln;
            b16x8 vfrag;
            #pragma unroll
            for (int j = 0; j < 8; ++j) vfrag[j] = (__bf16)vrow[(size_t)j * 2048];
            oacc[n] = __builtin_amdgcn_mfma_f32_16x16x32_bf16(pa, vfrag, oacc[n], 0, 0, 0);
        }
        __syncthreads();
    }

    // ---- epilogue: out[bh][row][d2][dim], C-frag row=quad*4+r, col=n*16+ln
    float* ob = out + base;
    #pragma unroll
    for (int n = 0; n < 4; ++n)
        #pragma unroll
        for (int r = 0; r < 4; ++r)
            ob[(size_t)(rowbase + r) * 2048 + n * 16 + ln] = oacc[n][r];
}

extern "C" void kernel_launch(void* const* d_in, const int* in_sizes, int n_in,
                              void* d_out, int out_size, void* d_ws, size_t ws_size,
                              hipStream_t stream) {
    const float* q  = (const float*)d_in[0];
    const float* k  = (const float*)d_in[1];
    const float* v  = (const float*)d_in[2];
    const float* am = (const float*)d_in[3];
    const float* hm = (const float*)d_in[4];
    float* out   = (float*)d_out;
    float* probs = out + 16777216;   // out is (2,8,512,32,64); probs is (512,512,512)

    dim3 grid(4096), block(256);
    hipLaunchKernelGGL(axial_attn_kernel, grid, block, 0, stream,
                       q, k, v, am, hm, out, probs);
}